// Round 2
// baseline (256.635 us; speedup 1.0000x reference)
//
#include <hip/hip_runtime.h>

#define LOG2E 1.44269504088896340736f
#define LN2   0.69314718055994530942f

typedef short bf4 __attribute__((ext_vector_type(4)));   // 4 bf16 = one 16x16x16 A/B frag (2 VGPRs)
typedef float f4  __attribute__((ext_vector_type(4)));   // 4 f32  = one 16x16 C/D frag

static __device__ __forceinline__ unsigned short f2bf_rne(float f) {
    unsigned u = __float_as_uint(f);
    u += 0x7FFFu + ((u >> 16) & 1u);
    return (unsigned short)(u >> 16);
}
// pack two f32 -> two bf16 (truncation; same numerics as the passing kernel)
static __device__ __forceinline__ unsigned pack_bf_trunc(float lo, float hi) {
    return __builtin_amdgcn_perm(__float_as_uint(hi), __float_as_uint(lo), 0x07060302u);
}

// 16x16x16 bf16 MFMA. C/D layout (col=lane&15, row=4*(lane>>4)+reg) is
// IDENTICAL to the B-operand layout (n=lane&15, k=4*(lane>>4)+j), so D
// (after scale+pack) feeds the next step's B with zero cross-lane movement.
static __device__ __forceinline__ f4 mfma16(bf4 a, bf4 b, f4 c) {
#if __has_builtin(__builtin_amdgcn_mfma_f32_16x16x16bf16_1k)
    return __builtin_amdgcn_mfma_f32_16x16x16bf16_1k(a, b, c, 0, 0, 0);
#else
    f4 d;
    asm("v_mfma_f32_16x16x16_bf16 %0, %1, %2, %3" : "=v"(d) : "v"(a), "v"(b), "v"(c));
    return d;
#endif
}
static __device__ __forceinline__ void mfma_fence() {
#if !__has_builtin(__builtin_amdgcn_mfma_f32_16x16x16bf16_1k)
    asm volatile("s_nop 7\ns_nop 7");   // asm fallback: MFMA->VALU read hazard
#endif
}

// ============================================================================
// Kernel 1: operator products, TWO independent chunks per wave (c and c+8),
// P fully in registers for both chains.
//   Op_t = mask_t ? D_t * M^T : I,  D_t = diag(exp(em_t) * 2^-7), M = exp(tr)
//   P_c  = Op_{t0+63} ... Op_{t0}   (64x64), dumped bf16 as P^T.
// Branchless per-step mask (compute + select) keeps everything in one basic
// block so the compiler interleaves the two chains' MFMA/VALU/LDS streams —
// in-wave ILP hides the per-step serial-chain latency that bounded round-1.
// waves_per_eu(2) -> 256-reg budget: afr(32, shared) + 2x bfr(32) + 2x dq(16)
// + acc(16) + misc fits in arch VGPRs, killing the AGPR-shuffle VALU bloat.
// ============================================================================
__global__ __attribute__((amdgpu_flat_work_group_size(64, 64), amdgpu_waves_per_eu(2, 4)))
void crf_scan(const int* __restrict__ yg, const float* __restrict__ em,
              const float* __restrict__ tr, unsigned short* __restrict__ Pg)
{
    constexpr int T = 1024;
    const int cA = blockIdx.x, b = blockIdx.y, cB = cA + 8;
    const int lane = threadIdx.x, nl = lane & 15, q = lane >> 4;

    __shared__ __align__(16) float d_sh[2][64];

    // ---- constant A-fragments of M^T: A[m][k] = exp(tr[k][m]).
    //      tile (mt,kt), lane(q,nl): m = 16mt+nl, k = 16kt+4q+j ----
    bf4 afr[4][4];
    #pragma unroll
    for (int mt = 0; mt < 4; ++mt)
        #pragma unroll
        for (int kt = 0; kt < 4; ++kt) {
            bf4 v;
            #pragma unroll
            for (int j = 0; j < 4; ++j) {
                const int k = 16 * kt + 4 * q + j, m = 16 * mt + nl;
                v[j] = (short)f2bf_rne(exp2f(tr[k * 64 + m] * LOG2E));
            }
            afr[mt][kt] = v;
        }

    // ---- P = I in B-fragments: bfr[kt][nt][j] = P[16kt+4q+j][16nt+nl] ----
    bf4 bfrA[4][4], bfrB[4][4];
    #pragma unroll
    for (int kt = 0; kt < 4; ++kt)
        #pragma unroll
        for (int nt = 0; nt < 4; ++nt) {
            bf4 v;
            #pragma unroll
            for (int j = 0; j < 4; ++j)
                v[j] = (short)((kt == nt && nl == 4 * q + j) ? 0x3F80 : 0);
            bfrA[kt][nt] = v;
            bfrB[kt][nt] = v;
        }

    const float* emb = em + (size_t)b * T * 64;
    const int t0A = 1 + 64 * cA;                       // cA in 0..7 -> t0A+64 <= 513
    const int t0B = 1 + 64 * cB;
    const int nsB = (cB == 15) ? 63 : 64;

    const unsigned long long mskA = __ballot(yg[b * T + t0A + lane] != 0);
    int tlB = t0B + lane; if (tlB > T - 1) tlB = T - 1;
    const unsigned long long mskB = __ballot(lane < nsB && yg[b * T + tlB] != 0);

    float ldA = emb[t0A * 64 + lane];                  // emission prefetch (1 deep/chain)
    float ldB = emb[t0B * 64 + lane];

    // one step of one chain: C = M^T * P, scale rows by d, pack, select
    auto step = [&](bf4 (&bfr)[4][4], const f4 (&dq)[4], bool act) {
        #pragma unroll
        for (int nt = 0; nt < 4; ++nt) {
            f4 acc[4];
            #pragma unroll
            for (int mt = 0; mt < 4; ++mt) {
                f4 a = mfma16(afr[mt][0], bfr[0][nt], (f4)(0.0f));
                a = mfma16(afr[mt][1], bfr[1][nt], a);
                a = mfma16(afr[mt][2], bfr[2][nt], a);
                a = mfma16(afr[mt][3], bfr[3][nt], a);
                acc[mt] = a;
            }
            mfma_fence();
            #pragma unroll
            for (int mt = 0; mt < 4; ++mt) {
                union { uint2 u; bf4 v2; } wv, od;
                od.v2 = bfr[mt][nt];
                wv.u.x = pack_bf_trunc(acc[mt][0] * dq[mt][0], acc[mt][1] * dq[mt][1]);
                wv.u.y = pack_bf_trunc(acc[mt][2] * dq[mt][2], acc[mt][3] * dq[mt][3]);
                wv.u.x = act ? wv.u.x : od.u.x;        // inactive step == identity op
                wv.u.y = act ? wv.u.y : od.u.y;
                bfr[mt][nt] = wv.v2;                   // new k-tile kt'=mt of column nt
            }
        }
    };

    for (int s = 0; s < 64; ++s) {
        const int tnA = t0A + s + 1;                   // always in-bounds (<=513)
        int tnB = t0B + s + 1; if (tnB > T - 1) tnB = T - 1;
        const float lnA = emb[tnA * 64 + lane];
        const float lnB = emb[tnB * 64 + lane];

        d_sh[0][lane] = exp2f(ldA * LOG2E - 7.0f);     // d[state=lane], chain A
        d_sh[1][lane] = exp2f(ldB * LOG2E - 7.0f);     // chain B
        // d quads for my C rows 16mt+4q+r (single wave: DS in-order, no barrier)
        f4 dqA[4], dqB[4];
        #pragma unroll
        for (int mt = 0; mt < 4; ++mt) {
            dqA[mt] = *(const f4*)&d_sh[0][16 * mt + 4 * q];
            dqB[mt] = *(const f4*)&d_sh[1][16 * mt + 4 * q];
        }

        const bool aA = (mskA >> s) & 1ull;
        const bool aB = (mskB >> s) & 1ull;
        step(bfrA, dqA, aA);
        step(bfrB, dqB, aB);

        ldA = lnA; ldB = lnB;
    }

    // ---- dump P^T for both chunks: Pg[(b*16+c)*4096 + n*64 + i] = P_c[i][n]
    //      lane holds P[16kt+4q+j][16nt+nl], j=0..3 contiguous -> 8B stores ----
    unsigned short* pgA = Pg + ((size_t)(b * 16 + cA) << 12);
    unsigned short* pgB = Pg + ((size_t)(b * 16 + cB) << 12);
    #pragma unroll
    for (int nt = 0; nt < 4; ++nt)
        #pragma unroll
        for (int kt = 0; kt < 4; ++kt) {
            *(uint2*)(pgA + (16 * nt + nl) * 64 + 16 * kt + 4 * q) =
                *(const uint2*)&bfrA[kt][nt];
            *(uint2*)(pgB + (16 * nt + nl) * 64 + 16 * kt + 4 * q) =
                *(const uint2*)&bfrB[kt][nt];
        }
}

// ============================================================================
// Kernel 2: per-batch combine, 4 waves/block (unchanged from round-1).
//   wave 0 : v = P_15 ... P_0 * exp(e0 - M0) with 1-chunk-ahead double-buffered
//            P prefetch, exact-pow2 re-centering per chunk.
//   waves 1-3 : gather scores (emission + transition) + masked-step count.
// ============================================================================
__global__ __attribute__((amdgpu_flat_work_group_size(256, 256)))
void crf_combine(const int* __restrict__ yg, const float* __restrict__ em,
                 const float* __restrict__ tr, const unsigned short* __restrict__ Pg,
                 float* __restrict__ out)
{
    constexpr int T = 1024;
    const int b = blockIdx.x, tid = threadIdx.x;
    const int w = tid >> 6, j = tid & 63;

    __shared__ __align__(16) float v_sh[64];
    __shared__ float red[3][4];

    float ep = 0.f, tp = 0.f; int cnt = 0;
    float v = 0.f, L = 0.f, vs = 0.f;

    if (w == 0) {
        const float e0 = em[(size_t)b * T * 64 + j];
        float M0 = e0;
        #pragma unroll
        for (int o = 32; o > 0; o >>= 1) M0 = fmaxf(M0, __shfl_xor(M0, o, 64));
        v = exp2f((e0 - M0) * LOG2E);
        L = M0;

        const unsigned short* row = Pg + ((size_t)(b * 16) << 12) + j * 64; // col j of P_c
        uint4 pA[8], pB[8];
        #pragma unroll
        for (int r = 0; r < 8; ++r) pA[r] = *(const uint4*)(row + r * 8);

#define CHUNK_STEP(CUR, NXT, CIDX)                                                 \
        do {                                                                       \
            if ((CIDX) + 1 < 16) {  /* prefetch next chunk: independent of v */    \
                const unsigned short* rn = row + ((size_t)((CIDX) + 1) << 12);     \
                _Pragma("unroll")                                                  \
                for (int r = 0; r < 8; ++r) NXT[r] = *(const uint4*)(rn + r * 8);  \
            }                                                                      \
            v_sh[j] = v;                            /* single wave: in-order DS */ \
            float s0 = 0.f, s1 = 0.f, s2 = 0.f, s3 = 0.f;                          \
            _Pragma("unroll")                                                      \
            for (int r = 0; r < 8; ++r) {                                          \
                const uint4 qq = CUR[r];                                           \
                const float* vp = &v_sh[r * 8];                                    \
                s0 = fmaf(__uint_as_float(qq.x << 16),         vp[0], s0);         \
                s1 = fmaf(__uint_as_float(qq.x & 0xFFFF0000u), vp[1], s1);         \
                s2 = fmaf(__uint_as_float(qq.y << 16),         vp[2], s2);         \
                s3 = fmaf(__uint_as_float(qq.y & 0xFFFF0000u), vp[3], s3);         \
                s0 = fmaf(__uint_as_float(qq.z << 16),         vp[4], s0);         \
                s1 = fmaf(__uint_as_float(qq.z & 0xFFFF0000u), vp[5], s1);         \
                s2 = fmaf(__uint_as_float(qq.w << 16),         vp[6], s2);         \
                s3 = fmaf(__uint_as_float(qq.w & 0xFFFF0000u), vp[7], s3);         \
            }                                                                      \
            float s = (s0 + s1) + (s2 + s3);                                       \
            const unsigned sb =                                                    \
                (unsigned)__builtin_amdgcn_readlane((int)__float_as_uint(s), 0);   \
            const int ef = (int)((sb >> 23) & 0xFF);                               \
            if (ef > 0 && ef < 255 && ef != 127) {  /* exact-pow2 re-center */     \
                const int E = ef - 127;                                            \
                s *= __uint_as_float((unsigned)(127 - E) << 23);                   \
                L += (float)E * LN2;                                               \
            }                                                                      \
            v = s;                                                                 \
        } while (0)

        for (int cc = 0; cc < 16; cc += 2) {
            CHUNK_STEP(pA, pB, cc);
            CHUNK_STEP(pB, pA, cc + 1);
        }
#undef CHUNK_STEP

        vs = v;
        #pragma unroll
        for (int o = 32; o > 0; o >>= 1) vs += __shfl_xor(vs, o, 64);
    } else {
        // ---- scores + unmasked-step count, waves 1..3 (stride 192 over t) ----
        const int* yb = yg + b * T;
        const int wt = tid - 64;                      // 0..191
        for (int t = 1 + wt; t < T; t += 192) {
            const int yt = yb[t];
            if (yt != 0) {
                ++cnt;
                tp += tr[yb[t - 1] * 64 + yt];
                ep += em[((size_t)b * T + t) * 64 + yt];
            }
        }
        if (tid == 64) {
            const int y0 = yb[0];
            if (y0 != 0) ep += em[(size_t)b * T * 64 + y0];
        }
        #pragma unroll
        for (int o = 32; o > 0; o >>= 1) {
            ep  += __shfl_xor(ep, o, 64);
            tp  += __shfl_xor(tp, o, 64);
            cnt += __shfl_xor(cnt, o, 64);
        }
        if (j == 0) { red[0][w] = ep; red[1][w] = tp; red[2][w] = (float)cnt; }
    }
    __syncthreads();

    if (tid == 0) {
        const float eps = red[0][1] + red[0][2] + red[0][3];
        const float tps = red[1][1] + red[1][2] + red[1][3];
        const float cs  = red[2][1] + red[2][2] + red[2][3];
        const float logz = L + 7.0f * LN2 * cs + __log2f(vs) * LN2;
        atomicAdd(out, (eps + tps - logz) * (-1.0f / 256.0f));
    }
}

extern "C" void kernel_launch(void* const* d_in, const int* in_sizes, int n_in,
                              void* d_out, int out_size, void* d_ws, size_t ws_size,
                              hipStream_t stream) {
    const int*   y  = (const int*)d_in[0];
    const float* em = (const float*)d_in[1];
    const float* tr = (const float*)d_in[2];
    float* out = (float*)d_out;
    unsigned short* Pg = (unsigned short*)d_ws;   // needs 256*16*4096*2 = 32 MB

    hipMemsetAsync(out, 0, sizeof(float), stream);
    crf_scan<<<dim3(8, 256), dim3(64), 0, stream>>>(y, em, tr, Pg);
    crf_combine<<<dim3(256), dim3(256), 0, stream>>>(y, em, tr, Pg, out);
}

// Round 3
// 203.384 us; speedup vs baseline: 1.2618x; 1.2618x over previous
//
#include <hip/hip_runtime.h>

#define LOG2E 1.44269504088896340736f
#define LN2   0.69314718055994530942f

typedef short bf8 __attribute__((ext_vector_type(8)));   // 8 bf16 = one 16x16x32 A/B frag (4 VGPRs)
typedef float f4  __attribute__((ext_vector_type(4)));   // 4 f32  = one 16x16 C/D frag

static __device__ __forceinline__ unsigned short f2bf_rne(float f) {
    unsigned u = __float_as_uint(f);
    u += 0x7FFFu + ((u >> 16) & 1u);
    return (unsigned short)(u >> 16);
}
// pack two f32 -> two bf16 (truncation; same numerics as the passing kernels)
static __device__ __forceinline__ unsigned pack_bf_trunc(float lo, float hi) {
    return __builtin_amdgcn_perm(__float_as_uint(hi), __float_as_uint(lo), 0x07060302u);
}

// ============================================================================
// Kernel 1: per-(batch, 64-step chunk) operator product, P fully in registers,
// using the FAST gfx950 16x16x32 bf16 MFMA (~4.85 cyc vs ~16.6 for the legacy
// 16x16x16 shape that bounded rounds 1-2).
//
//   Op_t = mask_t ? D_t * M^T : I,  D_t = diag(exp(em_t) * 2^-7), M = exp(tr)
//   P_c  = Op_{t0+63} ... Op_{t0}   (64x64), dumped bf16 as P^T.
//
// Layout trick (zero cross-lane D->B): 16x16x32 B-frag has k = 8q+j (granule
// 8), C/D has row = 4q+r (granule 4). Store P's rows in fragment-slot order
// l = 32*kt + 8*q + j (natural), and map MFMA output tile mt to global rows
//   g(mt, m=4q+r) = 32*(mt>>1) + 8*q + 4*(mt&1) + r.
// Then tile mt's output at lane-group q IS slot l = 32*(mt>>1)+8q+4*(mt&1)+r
// of the same lane: acc[2kt] -> dwords 0,1 and acc[2kt+1] -> dwords 2,3 of
// bfr[kt]. The row permutation is folded into the A-fragments at setup (free).
// ============================================================================
__global__ __attribute__((amdgpu_flat_work_group_size(64, 64), amdgpu_waves_per_eu(2, 4)))
void crf_scan(const int* __restrict__ yg, const float* __restrict__ em,
              const float* __restrict__ tr, unsigned short* __restrict__ Pg)
{
    constexpr int T = 1024;
    const int c = blockIdx.x, b = blockIdx.y;
    const int lane = threadIdx.x, nl = lane & 15, q = lane >> 4;

    __shared__ __align__(16) float d_sh[64];

    // ---- A-fragments of M^T with permuted rows:
    //      afr[mt][ka], lane(q,nl), elem j:  A[m=nl][k=8q+j (in K-tile ka)]
    //        = M^T[g(mt,nl)][32ka+8q+j] = exp(tr[(32ka+8q+j)*64 + g(mt,nl)])
    bf8 afr[4][2];
    #pragma unroll
    for (int mt = 0; mt < 4; ++mt) {
        const int g = 32 * (mt >> 1) + 8 * (nl >> 2) + 4 * (mt & 1) + (nl & 3);
        #pragma unroll
        for (int ka = 0; ka < 2; ++ka) {
            bf8 v;
            #pragma unroll
            for (int j = 0; j < 8; ++j) {
                const int k = 32 * ka + 8 * q + j;
                v[j] = (short)f2bf_rne(exp2f(tr[k * 64 + g] * LOG2E));
            }
            afr[mt][ka] = v;
        }
    }

    // ---- P = I in B-fragments: bfr[kt][nt][j] = P[32kt+8q+j][16nt+nl] ----
    bf8 bfr[2][4];
    #pragma unroll
    for (int kt = 0; kt < 2; ++kt)
        #pragma unroll
        for (int nt = 0; nt < 4; ++nt) {
            bf8 v;
            #pragma unroll
            for (int j = 0; j < 8; ++j)
                v[j] = (short)((32 * kt + 8 * q + j == 16 * nt + nl) ? 0x3F80 : 0);
            bfr[kt][nt] = v;
        }

    const int t0 = 1 + 64 * c;
    const int nsteps = (c == 15) ? 63 : 64;
    const float* emb = em + (size_t)b * T * 64;

    int tl = t0 + lane; if (tl > T - 1) tl = T - 1;
    const int yvl = yg[b * T + tl];
    const unsigned long long msk = __ballot(lane < nsteps && yvl != 0);

    float ldc = emb[t0 * 64 + lane];                  // emission prefetch (1 deep)
    for (int s = 0; s < nsteps; ++s) {
        int tn = t0 + s + 1; if (tn > T - 1) tn = T - 1;
        const float ldn = emb[tn * 64 + lane];
        if ((msk >> s) & 1ull) {                      // wave-uniform; active ~98.4%
            d_sh[lane] = exp2f(ldc * LOG2E - 7.0f);   // d[state=lane]
            // d quads for tile mt, regs r=0..3: rows g(mt,4q+r) ->
            // d_sh[32*(mt>>1) + 4*(mt&1) + 8q + r]  (broadcast f4, conflict-free;
            // single wave => DS pipe in-order, no barrier needed)
            f4 dq[4];
            #pragma unroll
            for (int mt = 0; mt < 4; ++mt)
                dq[mt] = *(const f4*)&d_sh[32 * (mt >> 1) + 4 * (mt & 1) + 8 * q];
            // per column-tile nt: 4 output tiles, each one 2-deep K=64 chain
            #pragma unroll
            for (int nt = 0; nt < 4; ++nt) {
                f4 acc[4];
                #pragma unroll
                for (int mt = 0; mt < 4; ++mt) {
                    f4 a = __builtin_amdgcn_mfma_f32_16x16x32_bf16(
                               afr[mt][0], bfr[0][nt], (f4)(0.0f), 0, 0, 0);
                    acc[mt] = __builtin_amdgcn_mfma_f32_16x16x32_bf16(
                               afr[mt][1], bfr[1][nt], a, 0, 0, 0);
                }
                // scale rows by d, pack: tile mt -> bfr[mt>>1], dword-half mt&1
                #pragma unroll
                for (int kt = 0; kt < 2; ++kt) {
                    union { uint4 u; bf8 v8; } wv;
                    wv.u.x = pack_bf_trunc(acc[2*kt  ][0] * dq[2*kt  ][0],
                                           acc[2*kt  ][1] * dq[2*kt  ][1]);
                    wv.u.y = pack_bf_trunc(acc[2*kt  ][2] * dq[2*kt  ][2],
                                           acc[2*kt  ][3] * dq[2*kt  ][3]);
                    wv.u.z = pack_bf_trunc(acc[2*kt+1][0] * dq[2*kt+1][0],
                                           acc[2*kt+1][1] * dq[2*kt+1][1]);
                    wv.u.w = pack_bf_trunc(acc[2*kt+1][2] * dq[2*kt+1][2],
                                           acc[2*kt+1][3] * dq[2*kt+1][3]);
                    bfr[kt][nt] = wv.v8;
                }
            }
        }
        ldc = ldn;
    }

    // ---- dump P^T: Pg[(b*16+c)*4096 + n*64 + i] = P_c[i][n]
    //      lane holds P[32kt+8q+j][16nt+nl], j contiguous -> 16B stores ----
    unsigned short* pg = Pg + ((size_t)(b * 16 + c) << 12);
    #pragma unroll
    for (int nt = 0; nt < 4; ++nt)
        #pragma unroll
        for (int kt = 0; kt < 2; ++kt)
            *(uint4*)(pg + (16 * nt + nl) * 64 + 32 * kt + 8 * q) =
                *(const uint4*)&bfr[kt][nt];
}

// ============================================================================
// Kernel 2: per-batch combine, 4 waves/block.
//   wave 0 : v = P_15 ... P_0 * exp(e0 - M0) with 1-chunk-ahead double-buffered
//            P prefetch, exact-pow2 re-centering per chunk.
//   waves 1-3 : gather scores (emission + transition) + masked-step count.
// ============================================================================
__global__ __attribute__((amdgpu_flat_work_group_size(256, 256)))
void crf_combine(const int* __restrict__ yg, const float* __restrict__ em,
                 const float* __restrict__ tr, const unsigned short* __restrict__ Pg,
                 float* __restrict__ out)
{
    constexpr int T = 1024;
    const int b = blockIdx.x, tid = threadIdx.x;
    const int w = tid >> 6, j = tid & 63;

    __shared__ __align__(16) float v_sh[64];
    __shared__ float red[3][4];

    float ep = 0.f, tp = 0.f; int cnt = 0;
    float v = 0.f, L = 0.f, vs = 0.f;

    if (w == 0) {
        const float e0 = em[(size_t)b * T * 64 + j];
        float M0 = e0;
        #pragma unroll
        for (int o = 32; o > 0; o >>= 1) M0 = fmaxf(M0, __shfl_xor(M0, o, 64));
        v = exp2f((e0 - M0) * LOG2E);
        L = M0;

        const unsigned short* row = Pg + ((size_t)(b * 16) << 12) + j * 64; // col j of P_c
        uint4 pA[8], pB[8];
        #pragma unroll
        for (int r = 0; r < 8; ++r) pA[r] = *(const uint4*)(row + r * 8);

#define CHUNK_STEP(CUR, NXT, CIDX)                                                 \
        do {                                                                       \
            if ((CIDX) + 1 < 16) {  /* prefetch next chunk: independent of v */    \
                const unsigned short* rn = row + ((size_t)((CIDX) + 1) << 12);     \
                _Pragma("unroll")                                                  \
                for (int r = 0; r < 8; ++r) NXT[r] = *(const uint4*)(rn + r * 8);  \
            }                                                                      \
            v_sh[j] = v;                            /* single wave: in-order DS */ \
            float s0 = 0.f, s1 = 0.f, s2 = 0.f, s3 = 0.f;                          \
            _Pragma("unroll")                                                      \
            for (int r = 0; r < 8; ++r) {                                          \
                const uint4 qq = CUR[r];                                           \
                const float* vp = &v_sh[r * 8];                                    \
                s0 = fmaf(__uint_as_float(qq.x << 16),         vp[0], s0);         \
                s1 = fmaf(__uint_as_float(qq.x & 0xFFFF0000u), vp[1], s1);         \
                s2 = fmaf(__uint_as_float(qq.y << 16),         vp[2], s2);         \
                s3 = fmaf(__uint_as_float(qq.y & 0xFFFF0000u), vp[3], s3);         \
                s0 = fmaf(__uint_as_float(qq.z << 16),         vp[4], s0);         \
                s1 = fmaf(__uint_as_float(qq.z & 0xFFFF0000u), vp[5], s1);         \
                s2 = fmaf(__uint_as_float(qq.w << 16),         vp[6], s2);         \
                s3 = fmaf(__uint_as_float(qq.w & 0xFFFF0000u), vp[7], s3);         \
            }                                                                      \
            float s = (s0 + s1) + (s2 + s3);                                       \
            const unsigned sb =                                                    \
                (unsigned)__builtin_amdgcn_readlane((int)__float_as_uint(s), 0);   \
            const int ef = (int)((sb >> 23) & 0xFF);                               \
            if (ef > 0 && ef < 255 && ef != 127) {  /* exact-pow2 re-center */     \
                const int E = ef - 127;                                            \
                s *= __uint_as_float((unsigned)(127 - E) << 23);                   \
                L += (float)E * LN2;                                               \
            }                                                                      \
            v = s;                                                                 \
        } while (0)

        for (int cc = 0; cc < 16; cc += 2) {
            CHUNK_STEP(pA, pB, cc);
            CHUNK_STEP(pB, pA, cc + 1);
        }
#undef CHUNK_STEP

        vs = v;
        #pragma unroll
        for (int o = 32; o > 0; o >>= 1) vs += __shfl_xor(vs, o, 64);
    } else {
        // ---- scores + unmasked-step count, waves 1..3 (stride 192 over t) ----
        const int* yb = yg + b * T;
        const int wt = tid - 64;                      // 0..191
        for (int t = 1 + wt; t < T; t += 192) {
            const int yt = yb[t];
            if (yt != 0) {
                ++cnt;
                tp += tr[yb[t - 1] * 64 + yt];
                ep += em[((size_t)b * T + t) * 64 + yt];
            }
        }
        if (tid == 64) {
            const int y0 = yb[0];
            if (y0 != 0) ep += em[(size_t)b * T * 64 + y0];
        }
        #pragma unroll
        for (int o = 32; o > 0; o >>= 1) {
            ep  += __shfl_xor(ep, o, 64);
            tp  += __shfl_xor(tp, o, 64);
            cnt += __shfl_xor(cnt, o, 64);
        }
        if (j == 0) { red[0][w] = ep; red[1][w] = tp; red[2][w] = (float)cnt; }
    }
    __syncthreads();

    if (tid == 0) {
        const float eps = red[0][1] + red[0][2] + red[0][3];
        const float tps = red[1][1] + red[1][2] + red[1][3];
        const float cs  = red[2][1] + red[2][2] + red[2][3];
        const float logz = L + 7.0f * LN2 * cs + __log2f(vs) * LN2;
        atomicAdd(out, (eps + tps - logz) * (-1.0f / 256.0f));
    }
}

extern "C" void kernel_launch(void* const* d_in, const int* in_sizes, int n_in,
                              void* d_out, int out_size, void* d_ws, size_t ws_size,
                              hipStream_t stream) {
    const int*   y  = (const int*)d_in[0];
    const float* em = (const float*)d_in[1];
    const float* tr = (const float*)d_in[2];
    float* out = (float*)d_out;
    unsigned short* Pg = (unsigned short*)d_ws;   // needs 256*16*4096*2 = 32 MB

    hipMemsetAsync(out, 0, sizeof(float), stream);
    crf_scan<<<dim3(16, 256), dim3(64), 0, stream>>>(y, em, tr, Pg);
    crf_combine<<<dim3(256), dim3(256), 0, stream>>>(y, em, tr, Pg, out);
}